// Round 15
// baseline (14389.618 us; speedup 1.0000x reference)
//
#include <hip/hip_runtime.h>
#include <cmath>

#define Bsz 64
#define Tsz 256
#define Hsz 1024
#define NWG 256
#define NTHR 512
#define GRPWG 64   // workgroups per b-group (4 groups of 64)
#define WROW 522   // padded uint stride per LDS weight row (512 used + 10 pad)

// native 4-float vector for nontemporal builtins (HIP float4 is a class type,
// which __builtin_nontemporal_* rejects)
typedef float f4raw __attribute__((ext_vector_type(4)));

// counted vmem wait + scheduler fence (rule #18: memory clobber alone does
// NOT stop register-only consumers from hoisting above the waitcnt)
#define WAITVM(N) do {                                            \
    asm volatile("s_waitcnt vmcnt(" #N ")" ::: "memory");         \
    __builtin_amdgcn_sched_barrier(0);                            \
} while (0)

// ---------------- device-global scratch -------------------------------------
__device__ float g_h[2][2][Bsz * Hsz];      // [layer][parity][b*H+k]
__device__ float g_pre[2][Bsz];             // [parity][b] gate partial accum
__device__ float g_an[Tsz * Bsz];           // [t][b]: x[b,min(t+1,T-1)] . v1
__device__ float g_v1[Hsz];
__device__ float g_v2[Hsz];
__device__ float g_c;
__device__ unsigned g_bar_cnt[4 * 32];      // padded per-group barrier state
__device__ unsigned g_bar_gen[4 * 32];
__device__ float g_gi0[(size_t)Tsz * Bsz * 3 * Hsz];  // 201 MB: x@Wih0^T + bih0

// ---------------- per-access coherent ops (NO L2-invalidating fences) -------
__device__ __forceinline__ float ldc(const float* p) {
    return __hip_atomic_load((const float*)p, __ATOMIC_RELAXED,
                             __HIP_MEMORY_SCOPE_AGENT);
}
__device__ __forceinline__ void stc(float* p, float v) {
    __hip_atomic_store(p, v, __ATOMIC_RELAXED, __HIP_MEMORY_SCOPE_AGENT);
}

// coherent 16B load: ONE request instead of 4 scalar atomic dwords.
// sc0 sc1 = strongest cache-bypass (>= agent scope): always-fresh.
__device__ __forceinline__ void ldc4_issue(const float* p, float4& v) {
    asm volatile("global_load_dwordx4 %0, %1, off sc0 sc1"
                 : "=v"(v) : "v"(p));
}

// bf16-pair (low = even k, high = odd k) -> float4 via shift/mask
__device__ __forceinline__ float4 bfx4(uint2 u) {
    float4 f;
    f.x = __uint_as_float(u.x << 16);
    f.y = __uint_as_float(u.x & 0xffff0000u);
    f.z = __uint_as_float(u.y << 16);
    f.w = __uint_as_float(u.y & 0xffff0000u);
    return f;
}

__device__ __forceinline__ unsigned rne_bf16_pair(float a, float b) {
    unsigned u0 = __float_as_uint(a);
    unsigned u1 = __float_as_uint(b);
    u0 = (u0 + 0x7fffu + ((u0 >> 16) & 1u)) >> 16;   // RNE to bf16
    u1 = (u1 + 0x7fffu + ((u1 >> 16) & 1u)) >> 16;
    return u0 | (u1 << 16);
}

// ---------------- per-b-group barrier (64 WGs) ------------------------------
__device__ __forceinline__ void groupbar(int bg, unsigned lgen) {
    __syncthreads();
    if (threadIdx.x == 0) {
        unsigned* cnt = &g_bar_cnt[bg * 32];
        unsigned* gen = &g_bar_gen[bg * 32];
        unsigned prev = __hip_atomic_fetch_add(cnt, 1u, __ATOMIC_RELAXED,
                                               __HIP_MEMORY_SCOPE_AGENT);
        if (prev == lgen * GRPWG - 1u) {
            __hip_atomic_store(gen, lgen, __ATOMIC_RELAXED,
                               __HIP_MEMORY_SCOPE_AGENT);
        } else {
            while (__hip_atomic_load(gen, __ATOMIC_RELAXED,
                                     __HIP_MEMORY_SCOPE_AGENT) < lgen)
                __builtin_amdgcn_s_sleep(1);
        }
    }
    __syncthreads();
}

// ---------------- init ------------------------------------------------------
__global__ void k_init(const float* __restrict__ h0,
                       const float* __restrict__ gW1, const float* __restrict__ gb1,
                       const float* __restrict__ gW2, const float* __restrict__ gb2,
                       const float* __restrict__ gWF, const float* __restrict__ gbF) {
    int blk = blockIdx.x, tid = threadIdx.x;
    if (blk < 256) {
        int idx = blk * 256 + tid;
        float v = h0[idx & (Hsz - 1)];
        g_h[0][0][idx] = v;
        g_h[1][0][idx] = v;
    } else if (blk == 256) {
        __shared__ float red[256];
        float s = 0.f;
        for (int j = tid; j < Hsz; j += 256) s += gWF[j] * (gb1[j] + gb2[j]);
        red[tid] = s;
        __syncthreads();
        for (int off = 128; off > 0; off >>= 1) {
            if (tid < off) red[tid] += red[tid + off];
            __syncthreads();
        }
        if (tid == 0) g_c = red[0] + gbF[0];
        if (tid < 128) ((float*)g_pre)[tid] = 0.f;
        if (tid >= 128 && tid < 256) {
            g_bar_cnt[tid - 128] = 0u;
            g_bar_gen[tid - 128] = 0u;
        }
    } else if (blk < 261) {
        int k = (blk - 257) * 256 + tid;
        float s = 0.f;
        for (int j = 0; j < Hsz; ++j) s += gWF[j] * gW1[(size_t)j * Hsz + k];
        g_v1[k] = s;
    } else {
        int k = (blk - 261) * 256 + tid;
        float s = 0.f;
        for (int j = 0; j < Hsz; ++j) s += gWF[j] * gW2[(size_t)j * Hsz + k];
        g_v2[k] = s;
    }
}

// ---------------- precompute an[t][b] = x[b, min(t+1,T-1)] . v1 -------------
__global__ void k_an(const float* __restrict__ x) {
    int blk = blockIdx.x, tid = threadIdx.x;
    int lane = tid & 63, wv = tid >> 6;
    for (int i = 0; i < 16; ++i) {
        int o = blk * 64 + wv * 16 + i;      // [0, 16384)
        int b = o >> 8, tt = o & 255;
        int ts = (tt + 1 < Tsz) ? tt + 1 : Tsz - 1;
        const float* xp = x + ((size_t)b * Tsz + ts) * Hsz;
        float s = 0.f;
        for (int k = lane; k < Hsz; k += 64) s += xp[k] * g_v1[k];
        for (int m = 32; m > 0; m >>= 1) s += __shfl_xor(s, m, 64);
        if (lane == 0) g_an[tt * 64 + b] = s;
    }
}

// ---------------- gi0 GEMM: g_gi0[t*64+b][n] = x[b,t,:].Wih0[n,:] + bih0[n] -
// g_gi0 is write-once/read-once -> non-temporal stores (don't pollute L3;
// L3 must retain the 25 MB fp32 L1 weight set across timesteps).
__global__ __launch_bounds__(256) void k_gemm(const float* __restrict__ x,
                                              const float* __restrict__ Wih,
                                              const float* __restrict__ bih) {
    __shared__ float As[16][132];
    __shared__ float Bs[16][132];
    const int tid = threadIdx.x;
    const int n0 = blockIdx.x * 128;   // 24 tiles
    const int m0 = blockIdx.y * 128;   // 128 tiles (C-row space r = t*64+b)
    const int tx = tid & 15, ty = tid >> 4;
    float acc[8][8] = {};

    for (int k0 = 0; k0 < Hsz; k0 += 16) {
#pragma unroll
        for (int i = 0; i < 2; ++i) {
            int task = tid * 2 + i;          // 0..511
            int rl = task >> 2;              // 0..127
            int kq = task & 3;
            int r = m0 + rl;
            int bb = r & 63, tt = r >> 6;
            float4 v = *(const float4*)(x + ((size_t)bb * Tsz + tt) * Hsz + k0 + kq * 4);
            As[kq * 4 + 0][rl] = v.x; As[kq * 4 + 1][rl] = v.y;
            As[kq * 4 + 2][rl] = v.z; As[kq * 4 + 3][rl] = v.w;
            float4 w = *(const float4*)(Wih + (size_t)(n0 + rl) * Hsz + k0 + kq * 4);
            Bs[kq * 4 + 0][rl] = w.x; Bs[kq * 4 + 1][rl] = w.y;
            Bs[kq * 4 + 2][rl] = w.z; Bs[kq * 4 + 3][rl] = w.w;
        }
        __syncthreads();
#pragma unroll
        for (int k = 0; k < 16; ++k) {
            float a[8], b[8];
            *(float4*)&a[0] = *(float4*)&As[k][ty * 8];
            *(float4*)&a[4] = *(float4*)&As[k][ty * 8 + 4];
            *(float4*)&b[0] = *(float4*)&Bs[k][tx * 8];
            *(float4*)&b[4] = *(float4*)&Bs[k][tx * 8 + 4];
#pragma unroll
            for (int i2 = 0; i2 < 8; ++i2)
#pragma unroll
                for (int j2 = 0; j2 < 8; ++j2) acc[i2][j2] += a[i2] * b[j2];
        }
        __syncthreads();
    }
#pragma unroll
    for (int i2 = 0; i2 < 8; ++i2) {
        int r = m0 + ty * 8 + i2;
        float* cp = g_gi0 + (size_t)r * (3 * Hsz) + n0 + tx * 8;
#pragma unroll
        for (int j2 = 0; j2 < 8; j2 += 4) {
            f4raw v;
            v.x = acc[i2][j2 + 0] + bih[n0 + tx * 8 + j2 + 0];
            v.y = acc[i2][j2 + 1] + bih[n0 + tx * 8 + j2 + 1];
            v.z = acc[i2][j2 + 2] + bih[n0 + tx * 8 + j2 + 2];
            v.w = acc[i2][j2 + 3] + bih[n0 + tx * 8 + j2 + 3];
            __builtin_nontemporal_store(v, (f4raw*)(cp + j2));
        }
    }
}

__device__ __forceinline__ float dot4(float4 a, float4 b) {
    return a.x * b.x + a.y * b.y + a.z * b.z + a.w * b.w;
}

// ---------------- one GRU layer phase ---------------------------------------
// 512 threads: 8 waves, wave w owns K-window [w*128, w*128+128).
// lane = (bi2: 8 b-pairs) x (ji2: 8 jn-pairs); WG tile 16b x 16jn.
// L0 weights: LDS-resident bf16 (s_wl). L1 weights: fp32 global (exact).
// Coherent state loads: FULL BURST (all 4 chunks issued up front, descending
// counted waits) - maximizes MLP on the ~600cy coherence-point loads.
template <bool IS_L1>
__device__ __forceinline__ void do_phase(
    int t, int b0, int jn0,
    const float* __restrict__ a0,                         // L1 only: gi input rows
    const float* __restrict__ st, float* __restrict__ ho, // state in/out
    const float* __restrict__ Wi, const float* __restrict__ Wh,
    const float* __restrict__ bi, const float* __restrict__ bh,
    const float* __restrict__ h0, const int* __restrict__ lens,
    float* __restrict__ outp, const unsigned* s_wl,
    float (*s_act)[2][16][36], float (*s_red)[4][16][16],
    const float* __restrict__ s_rst, float (*s_gs)[16]) {

    const int tid = threadIdx.x;
    const int wv = tid >> 6, lane = tid & 63;
    const int bi2 = (lane & 7) * 2, ji2 = (lane >> 3) * 2;
    const int kq0 = wv * 128;

    const float* wph[6];
    const float* wpi[6];
    int rb[6];
#pragma unroll
    for (int g = 0; g < 3; ++g)
#pragma unroll
        for (int dj = 0; dj < 2; ++dj) {
            if constexpr (IS_L1) {
                int row = g * Hsz + jn0 + ji2 + dj;
                wph[g * 2 + dj] = Wh + (size_t)row * Hsz;
                wpi[g * 2 + dj] = Wi + (size_t)row * Hsz;
            } else {
                rb[g * 2 + dj] = (g * 16 + ji2 + dj) * WROW;
            }
        }

    constexpr int NR = IS_L1 ? 4 : 2;   // staged float4 per lane per chunk
    constexpr int NM = IS_L1 ? 4 : 3;
    float acc[NM][2][2] = {};

    // issue a chunk's coherent loads (no wait; volatile asm keeps order)
    auto issue_chunk = [&](int c, float4* dst) {
        const int kb = kq0 + c * 32;
#pragma unroll
        for (int i = 0; i < NR; ++i) {
            int o = i * 64 + lane;
            int ts = o >> 7;                 // 0 always for L0
            int bb = (o >> 3) & 15, k4 = o & 7;
            int k = kb + k4 * 4;
            const float* p = (IS_L1 && ts == 0)
                ? (a0 + (size_t)(b0 + bb) * Hsz + k)
                : (st + (size_t)(b0 + bb) * Hsz + k);
            ldc4_issue(p, dst[i]);
        }
    };
    // apply reset patch + write to this wave's LDS window
    auto patch_write = [&](int c, float4* src) {
        const int kb = kq0 + c * 32;
#pragma unroll
        for (int i = 0; i < NR; ++i) {
            int o = i * 64 + lane;
            int ts = IS_L1 ? (o >> 7) : 0;
            int bb = (o >> 3) & 15, k4 = o & 7;
            int k = kb + k4 * 4;
            float4 v = src[i];
            if (!(IS_L1 && ts == 0)) {       // st rows get the reset patch
                float4 hv = *(const float4*)(h0 + k);
                if (s_rst[bb] != 0.f) v = hv;
            }
            *(float4*)&s_act[wv][ts][bb][k4 * 4] = v;
        }
    };
    auto compute_chunk = [&](int c) {
        const int kb = kq0 + c * 32;
#pragma unroll 2
        for (int kk = 0; kk < 32; kk += 4) {
            const int k = kb + kk;
            const int hs = IS_L1 ? 1 : 0;
            float4 hA = *(const float4*)&s_act[wv][hs][bi2][kk];
            float4 hB = *(const float4*)&s_act[wv][hs][bi2 + 1][kk];
            if constexpr (IS_L1) {
                float4 xA = *(const float4*)&s_act[wv][0][bi2][kk];
                float4 xB = *(const float4*)&s_act[wv][0][bi2 + 1][kk];
#pragma unroll
                for (int dj = 0; dj < 2; ++dj) {
                    float4 whr = *(const float4*)(wph[0 * 2 + dj] + k);
                    float4 whz = *(const float4*)(wph[1 * 2 + dj] + k);
                    float4 whn = *(const float4*)(wph[2 * 2 + dj] + k);
                    float4 wir = *(const float4*)(wpi[0 * 2 + dj] + k);
                    float4 wiz = *(const float4*)(wpi[1 * 2 + dj] + k);
                    float4 win = *(const float4*)(wpi[2 * 2 + dj] + k);
                    acc[0][0][dj] += dot4(xA, wir) + dot4(hA, whr);
                    acc[0][1][dj] += dot4(xB, wir) + dot4(hB, whr);
                    acc[1][0][dj] += dot4(xA, wiz) + dot4(hA, whz);
                    acc[1][1][dj] += dot4(xB, wiz) + dot4(hB, whz);
                    acc[2][0][dj] += dot4(xA, win);
                    acc[2][1][dj] += dot4(xB, win);
                    acc[3][0][dj] += dot4(hA, whn);
                    acc[3][1][dj] += dot4(hB, whn);
                }
            } else {
                const int kw = k >> 1;
#pragma unroll
                for (int dj = 0; dj < 2; ++dj) {
                    // LDS-resident bf16 weights (zero global traffic)
                    float4 whr = bfx4(*(const uint2*)&s_wl[rb[0 * 2 + dj] + kw]);
                    float4 whz = bfx4(*(const uint2*)&s_wl[rb[1 * 2 + dj] + kw]);
                    float4 whn = bfx4(*(const uint2*)&s_wl[rb[2 * 2 + dj] + kw]);
                    acc[0][0][dj] += dot4(hA, whr);
                    acc[0][1][dj] += dot4(hB, whr);
                    acc[1][0][dj] += dot4(hA, whz);
                    acc[1][1][dj] += dot4(hB, whz);
                    acc[2][0][dj] += dot4(hA, whn);
                    acc[2][1][dj] += dot4(hB, whn);
                }
            }
        }
    };

    // FULL-BURST schedule: all 4 chunks' coherent loads in flight at once.
    // Counted waits: our burst loads are the OLDEST in the vmcnt FIFO ->
    // under-wait impossible; compiler-inserted younger loads only over-wait.
    float4 C0[NR], C1[NR], C2[NR], C3[NR];
    issue_chunk(0, C0);
    issue_chunk(1, C1);
    issue_chunk(2, C2);
    issue_chunk(3, C3);
    if constexpr (IS_L1) WAITVM(12); else WAITVM(6);
    patch_write(0, C0); compute_chunk(0);
    if constexpr (IS_L1) WAITVM(8);  else WAITVM(4);
    patch_write(1, C1); compute_chunk(1);
    if constexpr (IS_L1) WAITVM(4);  else WAITVM(2);
    patch_write(2, C2); compute_chunk(2);
    WAITVM(0);
    patch_write(3, C3); compute_chunk(3);

    // ---- two-stage cross-wave reduce ---------------------------------------
    __syncthreads();
    if (wv >= 4) {
#pragma unroll
        for (int m = 0; m < NM; ++m)
#pragma unroll
            for (int db = 0; db < 2; ++db)
#pragma unroll
                for (int dj = 0; dj < 2; ++dj)
                    s_red[wv - 4][m][bi2 + db][ji2 + dj] = acc[m][db][dj];
    }
    __syncthreads();
    if (wv < 4) {
#pragma unroll
        for (int m = 0; m < NM; ++m)
#pragma unroll
            for (int db = 0; db < 2; ++db)
#pragma unroll
                for (int dj = 0; dj < 2; ++dj)
                    s_red[wv][m][bi2 + db][ji2 + dj] += acc[m][db][dj];
    }
    __syncthreads();

    // ---- epilogue ----------------------------------------------------------
    if (tid < 256) {
        const int ji = tid & 15, bI = tid >> 4;
        const int b = b0 + bI, jn = jn0 + ji;
        float hprev = ldc(st + (size_t)b * Hsz + jn);
        const int lb = lens[b];
        float s[NM];
#pragma unroll
        for (int m = 0; m < NM; ++m)
            s[m] = s_red[0][m][bI][ji] + s_red[1][m][bI][ji] +
                   s_red[2][m][bI][ji] + s_red[3][m][bI][ji];
        if (s_rst[bI] != 0.f) hprev = h0[jn];

        float pr, pz, pin, phn;
        if constexpr (IS_L1) {
            pr  = s[0] + bi[jn] + bh[jn];
            pz  = s[1] + bi[Hsz + jn] + bh[Hsz + jn];
            pin = s[2] + bi[2 * Hsz + jn];
            phn = s[3] + bh[2 * Hsz + jn];
        } else {
            // read-once stream: non-temporal (keep L3 for the L1 weights)
            const float* gp = g_gi0 + (size_t)(t * 64 + b) * (3 * Hsz) + jn;
            float g0r = __builtin_nontemporal_load(gp);
            float g0z = __builtin_nontemporal_load(gp + Hsz);
            float g0n = __builtin_nontemporal_load(gp + 2 * Hsz);
            pr  = g0r + s[0] + bh[jn];
            pz  = g0z + s[1] + bh[Hsz + jn];
            pin = g0n;
            phn = s[2] + bh[2 * Hsz + jn];
        }
        const float r_ = 1.f / (1.f + __expf(-pr));
        const float z_ = 1.f / (1.f + __expf(-pz));
        const float n_ = tanhf(pin + r_ * phn);
        const float hnew = (1.f - z_) * n_ + z_ * hprev;
        stc(ho + (size_t)b * Hsz + jn, hnew);                 // coherent state write
        if constexpr (IS_L1) {
            __builtin_nontemporal_store((t < lb) ? hnew : 0.f,
                                        &outp[((size_t)b * Tsz + t) * Hsz + jn]);
            s_gs[bI][ji] = hnew * g_v2[jn];
        }
    }
    if constexpr (IS_L1) {
        __syncthreads();
        if (tid < 16) {
            float sm = 0.f;
#pragma unroll
            for (int j = 0; j < 16; ++j) sm += s_gs[tid][j];
            atomicAdd(&g_pre[t & 1][b0 + tid], sm);
        }
    }
}

// ---------------- main persistent cooperative kernel ------------------------
// R13 config (512 thr, (512,1), 1 WG/CU LDS-bound, L0 weights LDS bf16, L1
// fp32) + full-burst coherent staging + nt hints on streams. VGPR may grow
// to ~200: free at 1 WG/CU (grid 256 always resident; 8 waves x 256 cap).
__global__ void __launch_bounds__(NTHR, 1)
k_main(const float* __restrict__ h0, const int* __restrict__ lens,
       const float* __restrict__ W_ih, const float* __restrict__ W_hh,
       const float* __restrict__ b_ih, const float* __restrict__ b_hh,
       float* __restrict__ outp, float* __restrict__ gatep) {
    __shared__ __align__(16) unsigned s_w[48 * WROW];    // 100.2 KB bf16 L0-Whh
    __shared__ __align__(16) float s_act[8][2][16][36];  // 36.9 KB
    __shared__ float s_red[4][4][16][16];                // 16.4 KB
    __shared__ float s_rst[16];
    __shared__ float s_gs[16][16];

    const int tid = threadIdx.x;
    const int wg = blockIdx.x, bg = wg >> 6, jg = wg & 63;
    const int b0 = bg * 16, jn0 = jg * 16;
    unsigned lgen = 0;

    const float* Wih1 = W_ih + (size_t)3 * Hsz * Hsz;
    const float* Whh1 = W_hh + (size_t)3 * Hsz * Hsz;
    const float* bi1 = b_ih + 3 * Hsz;
    const float* bh1 = b_hh + 3 * Hsz;

    // one-time: pack this WG's 48 L0-Whh rows into LDS as bf16 (RNE) pairs
    for (int idx = tid; idx < 48 * 512; idx += NTHR) {
        int r = idx >> 9, kw = idx & 511;
        int g = r >> 4, j = r & 15;
        const float* wrow = W_hh + ((size_t)(g * Hsz + jn0 + j)) * Hsz + kw * 2;
        s_w[r * WROW + kw] = rne_bf16_pair(wrow[0], wrow[1]);
    }
    __syncthreads();

    for (int t = 0; t < Tsz; ++t) {
        const int p0 = t & 1, p1 = p0 ^ 1;

        // prologue: reset flags from previous step's gate; emit gate_z
        if (tid < 16) {
            float rstf = 0.f;
            const int b = b0 + tid;
            const int lb = lens[b];
            if (t > 0) {
                const int tp = t - 1;
                const float pre = g_c + g_an[tp * 64 + b] + ldc(&g_pre[p1][b]);
                const bool il = (tp == lb - 1);
                rstf = (il || pre > 0.f) ? 1.f : 0.f;
                if (jg == 0) {
                    const float gt = il ? 1.f : 1.f / (1.f + __expf(-pre));
                    gatep[(size_t)b * Tsz + tp] = (tp < lb) ? gt : 0.f;
                }
            }
            s_rst[tid] = rstf;
        }
        __syncthreads();

        // layer 0: gi from precomputed g_gi0; h-matmul from LDS bf16 weights
        do_phase<false>(t, b0, jn0, nullptr,
                        g_h[0][p0], g_h[0][p1],
                        W_ih, W_hh, b_ih, b_hh, h0, lens,
                        outp, s_w, s_act, s_red, s_rst, s_gs);
        groupbar(bg, ++lgen);

        // zero next step's gate accumulator (parity p1, already consumed)
        if (jg == 0 && tid < 16) stc(&g_pre[p1][b0 + tid], 0.f);

        // layer 1: gi from fresh h0new; weights stream fp32 (exact)
        do_phase<true>(t, b0, jn0, g_h[0][p1],
                       g_h[1][p0], g_h[1][p1],
                       Wih1, Whh1, bi1, bh1, h0, lens,
                       outp, s_w, s_act, s_red, s_rst, s_gs);
        groupbar(bg, ++lgen);
    }

    // tail: gate_z for tp = T-1
    if (jg == 0 && tid < 16) {
        const int b = b0 + tid;
        const int lb = lens[b];
        const int tp = Tsz - 1;
        const float pre = g_c + g_an[tp * 64 + b] + ldc(&g_pre[tp & 1][b]);
        const bool il = (tp == lb - 1);
        const float gt = il ? 1.f : 1.f / (1.f + __expf(-pre));
        gatep[(size_t)b * Tsz + tp] = (tp < lb) ? gt : 0.f;
    }
}

// ---------------- host launcher ---------------------------------------------
extern "C" void kernel_launch(void* const* d_in, const int* in_sizes, int n_in,
                              void* d_out, int out_size, void* d_ws, size_t ws_size,
                              hipStream_t stream) {
    const float* x = (const float*)d_in[0];
    const float* h0 = (const float*)d_in[1];
    const int* lens = (const int*)d_in[2];
    const float* W_ih = (const float*)d_in[3];
    const float* W_hh = (const float*)d_in[4];
    const float* b_ih = (const float*)d_in[5];
    const float* b_hh = (const float*)d_in[6];
    const float* gW1 = (const float*)d_in[7];
    const float* gb1 = (const float*)d_in[8];
    const float* gW2 = (const float*)d_in[9];
    const float* gb2 = (const float*)d_in[10];
    const float* gWF = (const float*)d_in[11];
    const float* gbF = (const float*)d_in[12];
    float* outp = (float*)d_out;
    float* gatep = outp + (size_t)Bsz * Tsz * Hsz;

    hipLaunchKernelGGL(k_init, dim3(265), dim3(256), 0, stream,
                       h0, gW1, gb1, gW2, gb2, gWF, gbF);
    hipLaunchKernelGGL(k_an, dim3(256), dim3(256), 0, stream, x);
    hipLaunchKernelGGL(k_gemm, dim3(24, 128), dim3(256), 0, stream,
                       x, W_ih, b_ih);

    void* args[8] = { (void*)&h0, (void*)&lens, (void*)&W_ih, (void*)&W_hh,
                      (void*)&b_ih, (void*)&b_hh, (void*)&outp, (void*)&gatep };
    hipError_t err = hipLaunchCooperativeKernel((const void*)k_main, dim3(NWG), dim3(NTHR),
                                                args, 0, stream);
    (void)err;
}

// Round 16
// 14366.858 us; speedup vs baseline: 1.0016x; 1.0016x over previous
//
#include <hip/hip_runtime.h>
#include <cmath>

#define Bsz 64
#define Tsz 256
#define Hsz 1024
#define NWG 256
#define NTHR 512
#define GRPWG 64   // workgroups per b-group (4 groups of 64)
#define WROW 522   // padded uint stride per LDS weight row (512 used + 10 pad)

// counted vmem wait + scheduler fence (rule #18: memory clobber alone does
// NOT stop register-only consumers from hoisting above the waitcnt)
#define WAITVM(N) do {                                            \
    asm volatile("s_waitcnt vmcnt(" #N ")" ::: "memory");         \
    __builtin_amdgcn_sched_barrier(0);                            \
} while (0)

// ---------------- device-global scratch -------------------------------------
__device__ float g_h[2][2][Bsz * Hsz];      // [layer][parity][b*H+k]
__device__ float g_pre[2][Bsz];             // [parity][b] gate partial accum
__device__ float g_an[Tsz * Bsz];           // [t][b]: x[b,min(t+1,T-1)] . v1
__device__ float g_v1[Hsz];
__device__ float g_v2[Hsz];
__device__ float g_c;
__device__ unsigned g_bar_cnt[4 * 32];      // padded per-group barrier state
__device__ unsigned g_bar_gen[4 * 32];
__device__ float g_gi0[(size_t)Tsz * Bsz * 3 * Hsz];  // 201 MB: x@Wih0^T + bih0

// ---------------- per-access coherent ops (NO L2-invalidating fences) -------
__device__ __forceinline__ float ldc(const float* p) {
    return __hip_atomic_load((const float*)p, __ATOMIC_RELAXED,
                             __HIP_MEMORY_SCOPE_AGENT);
}
__device__ __forceinline__ void stc(float* p, float v) {
    __hip_atomic_store(p, v, __ATOMIC_RELAXED, __HIP_MEMORY_SCOPE_AGENT);
}

// coherent 16B load: ONE request instead of 4 scalar atomic dwords.
// sc0 sc1 = strongest cache-bypass (>= agent scope): always-fresh.
__device__ __forceinline__ void ldc4_issue(const float* p, float4& v) {
    asm volatile("global_load_dwordx4 %0, %1, off sc0 sc1"
                 : "=v"(v) : "v"(p));
}

// bf16-pair (low = even k, high = odd k) -> float4 via shift/mask
__device__ __forceinline__ float4 bfx4(uint2 u) {
    float4 f;
    f.x = __uint_as_float(u.x << 16);
    f.y = __uint_as_float(u.x & 0xffff0000u);
    f.z = __uint_as_float(u.y << 16);
    f.w = __uint_as_float(u.y & 0xffff0000u);
    return f;
}

__device__ __forceinline__ unsigned rne_bf16_pair(float a, float b) {
    unsigned u0 = __float_as_uint(a);
    unsigned u1 = __float_as_uint(b);
    u0 = (u0 + 0x7fffu + ((u0 >> 16) & 1u)) >> 16;   // RNE to bf16
    u1 = (u1 + 0x7fffu + ((u1 >> 16) & 1u)) >> 16;
    return u0 | (u1 << 16);
}

// ---------------- per-b-group barrier (64 WGs) ------------------------------
__device__ __forceinline__ void groupbar(int bg, unsigned lgen) {
    __syncthreads();
    if (threadIdx.x == 0) {
        unsigned* cnt = &g_bar_cnt[bg * 32];
        unsigned* gen = &g_bar_gen[bg * 32];
        unsigned prev = __hip_atomic_fetch_add(cnt, 1u, __ATOMIC_RELAXED,
                                               __HIP_MEMORY_SCOPE_AGENT);
        if (prev == lgen * GRPWG - 1u) {
            __hip_atomic_store(gen, lgen, __ATOMIC_RELAXED,
                               __HIP_MEMORY_SCOPE_AGENT);
        } else {
            while (__hip_atomic_load(gen, __ATOMIC_RELAXED,
                                     __HIP_MEMORY_SCOPE_AGENT) < lgen)
                __builtin_amdgcn_s_sleep(1);
        }
    }
    __syncthreads();
}

// ---------------- init ------------------------------------------------------
__global__ void k_init(const float* __restrict__ h0,
                       const float* __restrict__ gW1, const float* __restrict__ gb1,
                       const float* __restrict__ gW2, const float* __restrict__ gb2,
                       const float* __restrict__ gWF, const float* __restrict__ gbF) {
    int blk = blockIdx.x, tid = threadIdx.x;
    if (blk < 256) {
        int idx = blk * 256 + tid;
        float v = h0[idx & (Hsz - 1)];
        g_h[0][0][idx] = v;
        g_h[1][0][idx] = v;
    } else if (blk == 256) {
        __shared__ float red[256];
        float s = 0.f;
        for (int j = tid; j < Hsz; j += 256) s += gWF[j] * (gb1[j] + gb2[j]);
        red[tid] = s;
        __syncthreads();
        for (int off = 128; off > 0; off >>= 1) {
            if (tid < off) red[tid] += red[tid + off];
            __syncthreads();
        }
        if (tid == 0) g_c = red[0] + gbF[0];
        if (tid < 128) ((float*)g_pre)[tid] = 0.f;
        if (tid >= 128 && tid < 256) {
            g_bar_cnt[tid - 128] = 0u;
            g_bar_gen[tid - 128] = 0u;
        }
    } else if (blk < 261) {
        int k = (blk - 257) * 256 + tid;
        float s = 0.f;
        for (int j = 0; j < Hsz; ++j) s += gWF[j] * gW1[(size_t)j * Hsz + k];
        g_v1[k] = s;
    } else {
        int k = (blk - 261) * 256 + tid;
        float s = 0.f;
        for (int j = 0; j < Hsz; ++j) s += gWF[j] * gW2[(size_t)j * Hsz + k];
        g_v2[k] = s;
    }
}

// ---------------- precompute an[t][b] = x[b, min(t+1,T-1)] . v1 -------------
__global__ void k_an(const float* __restrict__ x) {
    int blk = blockIdx.x, tid = threadIdx.x;
    int lane = tid & 63, wv = tid >> 6;
    for (int i = 0; i < 16; ++i) {
        int o = blk * 64 + wv * 16 + i;      // [0, 16384)
        int b = o >> 8, tt = o & 255;
        int ts = (tt + 1 < Tsz) ? tt + 1 : Tsz - 1;
        const float* xp = x + ((size_t)b * Tsz + ts) * Hsz;
        float s = 0.f;
        for (int k = lane; k < Hsz; k += 64) s += xp[k] * g_v1[k];
        for (int m = 32; m > 0; m >>= 1) s += __shfl_xor(s, m, 64);
        if (lane == 0) g_an[tt * 64 + b] = s;
    }
}

// ---------------- gi0 GEMM: g_gi0[t*64+b][n] = x[b,t,:].Wih0[n,:] + bih0[n] -
__global__ __launch_bounds__(256) void k_gemm(const float* __restrict__ x,
                                              const float* __restrict__ Wih,
                                              const float* __restrict__ bih) {
    __shared__ float As[16][132];
    __shared__ float Bs[16][132];
    const int tid = threadIdx.x;
    const int n0 = blockIdx.x * 128;   // 24 tiles
    const int m0 = blockIdx.y * 128;   // 128 tiles (C-row space r = t*64+b)
    const int tx = tid & 15, ty = tid >> 4;
    float acc[8][8] = {};

    for (int k0 = 0; k0 < Hsz; k0 += 16) {
#pragma unroll
        for (int i = 0; i < 2; ++i) {
            int task = tid * 2 + i;          // 0..511
            int rl = task >> 2;              // 0..127
            int kq = task & 3;
            int r = m0 + rl;
            int bb = r & 63, tt = r >> 6;
            float4 v = *(const float4*)(x + ((size_t)bb * Tsz + tt) * Hsz + k0 + kq * 4);
            As[kq * 4 + 0][rl] = v.x; As[kq * 4 + 1][rl] = v.y;
            As[kq * 4 + 2][rl] = v.z; As[kq * 4 + 3][rl] = v.w;
            float4 w = *(const float4*)(Wih + (size_t)(n0 + rl) * Hsz + k0 + kq * 4);
            Bs[kq * 4 + 0][rl] = w.x; Bs[kq * 4 + 1][rl] = w.y;
            Bs[kq * 4 + 2][rl] = w.z; Bs[kq * 4 + 3][rl] = w.w;
        }
        __syncthreads();
#pragma unroll
        for (int k = 0; k < 16; ++k) {
            float a[8], b[8];
            *(float4*)&a[0] = *(float4*)&As[k][ty * 8];
            *(float4*)&a[4] = *(float4*)&As[k][ty * 8 + 4];
            *(float4*)&b[0] = *(float4*)&Bs[k][tx * 8];
            *(float4*)&b[4] = *(float4*)&Bs[k][tx * 8 + 4];
#pragma unroll
            for (int i2 = 0; i2 < 8; ++i2)
#pragma unroll
                for (int j2 = 0; j2 < 8; ++j2) acc[i2][j2] += a[i2] * b[j2];
        }
        __syncthreads();
    }
#pragma unroll
    for (int i2 = 0; i2 < 8; ++i2) {
        int r = m0 + ty * 8 + i2;
        float* cp = g_gi0 + (size_t)r * (3 * Hsz) + n0 + tx * 8;
#pragma unroll
        for (int j2 = 0; j2 < 8; j2 += 4) {
            float4 v;
            v.x = acc[i2][j2 + 0] + bih[n0 + tx * 8 + j2 + 0];
            v.y = acc[i2][j2 + 1] + bih[n0 + tx * 8 + j2 + 1];
            v.z = acc[i2][j2 + 2] + bih[n0 + tx * 8 + j2 + 2];
            v.w = acc[i2][j2 + 3] + bih[n0 + tx * 8 + j2 + 3];
            *(float4*)(cp + j2) = v;
        }
    }
}

__device__ __forceinline__ float dot4(float4 a, float4 b) {
    return a.x * b.x + a.y * b.y + a.z * b.z + a.w * b.w;
}

// ---------------- one GRU layer phase ---------------------------------------
// 512 threads: 8 waves, wave w owns K-window [w*128, w*128+128).
// lane = (bi2: 8 b-pairs) x (ji2: 8 jn-pairs); WG tile 16b x 16jn.
// L0 weights: LDS-resident bf16 (s_wl). L1 weights: fp32 global (exact).
// Coherent state loads: FULL BURST (all 4 chunks issued up front, descending
// counted waits). No nontemporal hints anywhere (R15: they cost +0.65 GB
// FETCH and +4% time by forfeiting gi0's L3 caching).
template <bool IS_L1>
__device__ __forceinline__ void do_phase(
    int t, int b0, int jn0,
    const float* __restrict__ a0,                         // L1 only: gi input rows
    const float* __restrict__ st, float* __restrict__ ho, // state in/out
    const float* __restrict__ Wi, const float* __restrict__ Wh,
    const float* __restrict__ bi, const float* __restrict__ bh,
    const float* __restrict__ h0, const int* __restrict__ lens,
    float* __restrict__ outp, const unsigned* s_wl,
    float (*s_act)[2][16][36], float (*s_red)[4][16][16],
    const float* __restrict__ s_rst, float (*s_gs)[16]) {

    const int tid = threadIdx.x;
    const int wv = tid >> 6, lane = tid & 63;
    const int bi2 = (lane & 7) * 2, ji2 = (lane >> 3) * 2;
    const int kq0 = wv * 128;

    const float* wph[6];
    const float* wpi[6];
    int rb[6];
#pragma unroll
    for (int g = 0; g < 3; ++g)
#pragma unroll
        for (int dj = 0; dj < 2; ++dj) {
            if constexpr (IS_L1) {
                int row = g * Hsz + jn0 + ji2 + dj;
                wph[g * 2 + dj] = Wh + (size_t)row * Hsz;
                wpi[g * 2 + dj] = Wi + (size_t)row * Hsz;
            } else {
                rb[g * 2 + dj] = (g * 16 + ji2 + dj) * WROW;
            }
        }

    constexpr int NR = IS_L1 ? 4 : 2;   // staged float4 per lane per chunk
    constexpr int NM = IS_L1 ? 4 : 3;
    float acc[NM][2][2] = {};

    // issue a chunk's coherent loads (no wait; volatile asm keeps order)
    auto issue_chunk = [&](int c, float4* dst) {
        const int kb = kq0 + c * 32;
#pragma unroll
        for (int i = 0; i < NR; ++i) {
            int o = i * 64 + lane;
            int ts = o >> 7;                 // 0 always for L0
            int bb = (o >> 3) & 15, k4 = o & 7;
            int k = kb + k4 * 4;
            const float* p = (IS_L1 && ts == 0)
                ? (a0 + (size_t)(b0 + bb) * Hsz + k)
                : (st + (size_t)(b0 + bb) * Hsz + k);
            ldc4_issue(p, dst[i]);
        }
    };
    // apply reset patch + write to this wave's LDS window
    auto patch_write = [&](int c, float4* src) {
        const int kb = kq0 + c * 32;
#pragma unroll
        for (int i = 0; i < NR; ++i) {
            int o = i * 64 + lane;
            int ts = IS_L1 ? (o >> 7) : 0;
            int bb = (o >> 3) & 15, k4 = o & 7;
            int k = kb + k4 * 4;
            float4 v = src[i];
            if (!(IS_L1 && ts == 0)) {       // st rows get the reset patch
                float4 hv = *(const float4*)(h0 + k);
                if (s_rst[bb] != 0.f) v = hv;
            }
            *(float4*)&s_act[wv][ts][bb][k4 * 4] = v;
        }
    };
    auto compute_chunk = [&](int c) {
        const int kb = kq0 + c * 32;
#pragma unroll 2
        for (int kk = 0; kk < 32; kk += 4) {
            const int k = kb + kk;
            const int hs = IS_L1 ? 1 : 0;
            float4 hA = *(const float4*)&s_act[wv][hs][bi2][kk];
            float4 hB = *(const float4*)&s_act[wv][hs][bi2 + 1][kk];
            if constexpr (IS_L1) {
                float4 xA = *(const float4*)&s_act[wv][0][bi2][kk];
                float4 xB = *(const float4*)&s_act[wv][0][bi2 + 1][kk];
#pragma unroll
                for (int dj = 0; dj < 2; ++dj) {
                    float4 whr = *(const float4*)(wph[0 * 2 + dj] + k);
                    float4 whz = *(const float4*)(wph[1 * 2 + dj] + k);
                    float4 whn = *(const float4*)(wph[2 * 2 + dj] + k);
                    float4 wir = *(const float4*)(wpi[0 * 2 + dj] + k);
                    float4 wiz = *(const float4*)(wpi[1 * 2 + dj] + k);
                    float4 win = *(const float4*)(wpi[2 * 2 + dj] + k);
                    acc[0][0][dj] += dot4(xA, wir) + dot4(hA, whr);
                    acc[0][1][dj] += dot4(xB, wir) + dot4(hB, whr);
                    acc[1][0][dj] += dot4(xA, wiz) + dot4(hA, whz);
                    acc[1][1][dj] += dot4(xB, wiz) + dot4(hB, whz);
                    acc[2][0][dj] += dot4(xA, win);
                    acc[2][1][dj] += dot4(xB, win);
                    acc[3][0][dj] += dot4(hA, whn);
                    acc[3][1][dj] += dot4(hB, whn);
                }
            } else {
                const int kw = k >> 1;
#pragma unroll
                for (int dj = 0; dj < 2; ++dj) {
                    // LDS-resident bf16 weights (zero global traffic)
                    float4 whr = bfx4(*(const uint2*)&s_wl[rb[0 * 2 + dj] + kw]);
                    float4 whz = bfx4(*(const uint2*)&s_wl[rb[1 * 2 + dj] + kw]);
                    float4 whn = bfx4(*(const uint2*)&s_wl[rb[2 * 2 + dj] + kw]);
                    acc[0][0][dj] += dot4(hA, whr);
                    acc[0][1][dj] += dot4(hB, whr);
                    acc[1][0][dj] += dot4(hA, whz);
                    acc[1][1][dj] += dot4(hB, whz);
                    acc[2][0][dj] += dot4(hA, whn);
                    acc[2][1][dj] += dot4(hB, whn);
                }
            }
        }
    };

    // FULL-BURST schedule: all 4 chunks' coherent loads in flight at once.
    // Counted waits: our burst loads are the OLDEST in the vmcnt FIFO ->
    // under-wait impossible; compiler-inserted younger loads only over-wait.
    float4 C0[NR], C1[NR], C2[NR], C3[NR];
    issue_chunk(0, C0);
    issue_chunk(1, C1);
    issue_chunk(2, C2);
    issue_chunk(3, C3);
    if constexpr (IS_L1) WAITVM(12); else WAITVM(6);
    patch_write(0, C0); compute_chunk(0);
    if constexpr (IS_L1) WAITVM(8);  else WAITVM(4);
    patch_write(1, C1); compute_chunk(1);
    if constexpr (IS_L1) WAITVM(4);  else WAITVM(2);
    patch_write(2, C2); compute_chunk(2);
    WAITVM(0);
    patch_write(3, C3); compute_chunk(3);

    // ---- two-stage cross-wave reduce ---------------------------------------
    __syncthreads();
    if (wv >= 4) {
#pragma unroll
        for (int m = 0; m < NM; ++m)
#pragma unroll
            for (int db = 0; db < 2; ++db)
#pragma unroll
                for (int dj = 0; dj < 2; ++dj)
                    s_red[wv - 4][m][bi2 + db][ji2 + dj] = acc[m][db][dj];
    }
    __syncthreads();
    if (wv < 4) {
#pragma unroll
        for (int m = 0; m < NM; ++m)
#pragma unroll
            for (int db = 0; db < 2; ++db)
#pragma unroll
                for (int dj = 0; dj < 2; ++dj)
                    s_red[wv][m][bi2 + db][ji2 + dj] += acc[m][db][dj];
    }
    __syncthreads();

    // ---- epilogue ----------------------------------------------------------
    if (tid < 256) {
        const int ji = tid & 15, bI = tid >> 4;
        const int b = b0 + bI, jn = jn0 + ji;
        float hprev = ldc(st + (size_t)b * Hsz + jn);
        const int lb = lens[b];
        float s[NM];
#pragma unroll
        for (int m = 0; m < NM; ++m)
            s[m] = s_red[0][m][bI][ji] + s_red[1][m][bI][ji] +
                   s_red[2][m][bI][ji] + s_red[3][m][bI][ji];
        if (s_rst[bI] != 0.f) hprev = h0[jn];

        float pr, pz, pin, phn;
        if constexpr (IS_L1) {
            pr  = s[0] + bi[jn] + bh[jn];
            pz  = s[1] + bi[Hsz + jn] + bh[Hsz + jn];
            pin = s[2] + bi[2 * Hsz + jn];
            phn = s[3] + bh[2 * Hsz + jn];
        } else {
            const float* gp = g_gi0 + (size_t)(t * 64 + b) * (3 * Hsz) + jn;
            float g0r = gp[0];
            float g0z = gp[Hsz];
            float g0n = gp[2 * Hsz];
            pr  = g0r + s[0] + bh[jn];
            pz  = g0z + s[1] + bh[Hsz + jn];
            pin = g0n;
            phn = s[2] + bh[2 * Hsz + jn];
        }
        const float r_ = 1.f / (1.f + __expf(-pr));
        const float z_ = 1.f / (1.f + __expf(-pz));
        const float n_ = tanhf(pin + r_ * phn);
        const float hnew = (1.f - z_) * n_ + z_ * hprev;
        stc(ho + (size_t)b * Hsz + jn, hnew);                 // coherent state write
        if constexpr (IS_L1) {
            outp[((size_t)b * Tsz + t) * Hsz + jn] = (t < lb) ? hnew : 0.f;
            s_gs[bI][ji] = hnew * g_v2[jn];
        }
    }
    if constexpr (IS_L1) {
        __syncthreads();
        if (tid < 16) {
            float sm = 0.f;
#pragma unroll
            for (int j = 0; j < 16; ++j) sm += s_gs[tid][j];
            atomicAdd(&g_pre[t & 1][b0 + tid], sm);
        }
    }
}

// ---------------- main persistent cooperative kernel ------------------------
// R13 config (512 thr, (512,1), 1 WG/CU LDS-bound, L0 weights LDS bf16, L1
// fp32) + full-burst coherent staging. NO nontemporal hints (R15 regression).
__global__ void __launch_bounds__(NTHR, 1)
k_main(const float* __restrict__ h0, const int* __restrict__ lens,
       const float* __restrict__ W_ih, const float* __restrict__ W_hh,
       const float* __restrict__ b_ih, const float* __restrict__ b_hh,
       float* __restrict__ outp, float* __restrict__ gatep) {
    __shared__ __align__(16) unsigned s_w[48 * WROW];    // 100.2 KB bf16 L0-Whh
    __shared__ __align__(16) float s_act[8][2][16][36];  // 36.9 KB
    __shared__ float s_red[4][4][16][16];                // 16.4 KB
    __shared__ float s_rst[16];
    __shared__ float s_gs[16][16];

    const int tid = threadIdx.x;
    const int wg = blockIdx.x, bg = wg >> 6, jg = wg & 63;
    const int b0 = bg * 16, jn0 = jg * 16;
    unsigned lgen = 0;

    const float* Wih1 = W_ih + (size_t)3 * Hsz * Hsz;
    const float* Whh1 = W_hh + (size_t)3 * Hsz * Hsz;
    const float* bi1 = b_ih + 3 * Hsz;
    const float* bh1 = b_hh + 3 * Hsz;

    // one-time: pack this WG's 48 L0-Whh rows into LDS as bf16 (RNE) pairs
    for (int idx = tid; idx < 48 * 512; idx += NTHR) {
        int r = idx >> 9, kw = idx & 511;
        int g = r >> 4, j = r & 15;
        const float* wrow = W_hh + ((size_t)(g * Hsz + jn0 + j)) * Hsz + kw * 2;
        s_w[r * WROW + kw] = rne_bf16_pair(wrow[0], wrow[1]);
    }
    __syncthreads();

    for (int t = 0; t < Tsz; ++t) {
        const int p0 = t & 1, p1 = p0 ^ 1;

        // prologue: reset flags from previous step's gate; emit gate_z
        if (tid < 16) {
            float rstf = 0.f;
            const int b = b0 + tid;
            const int lb = lens[b];
            if (t > 0) {
                const int tp = t - 1;
                const float pre = g_c + g_an[tp * 64 + b] + ldc(&g_pre[p1][b]);
                const bool il = (tp == lb - 1);
                rstf = (il || pre > 0.f) ? 1.f : 0.f;
                if (jg == 0) {
                    const float gt = il ? 1.f : 1.f / (1.f + __expf(-pre));
                    gatep[(size_t)b * Tsz + tp] = (tp < lb) ? gt : 0.f;
                }
            }
            s_rst[tid] = rstf;
        }
        __syncthreads();

        // layer 0: gi from precomputed g_gi0; h-matmul from LDS bf16 weights
        do_phase<false>(t, b0, jn0, nullptr,
                        g_h[0][p0], g_h[0][p1],
                        W_ih, W_hh, b_ih, b_hh, h0, lens,
                        outp, s_w, s_act, s_red, s_rst, s_gs);
        groupbar(bg, ++lgen);

        // zero next step's gate accumulator (parity p1, already consumed)
        if (jg == 0 && tid < 16) stc(&g_pre[p1][b0 + tid], 0.f);

        // layer 1: gi from fresh h0new; weights stream fp32 (exact)
        do_phase<true>(t, b0, jn0, g_h[0][p1],
                       g_h[1][p0], g_h[1][p1],
                       Wih1, Whh1, bi1, bh1, h0, lens,
                       outp, s_w, s_act, s_red, s_rst, s_gs);
        groupbar(bg, ++lgen);
    }

    // tail: gate_z for tp = T-1
    if (jg == 0 && tid < 16) {
        const int b = b0 + tid;
        const int lb = lens[b];
        const int tp = Tsz - 1;
        const float pre = g_c + g_an[tp * 64 + b] + ldc(&g_pre[tp & 1][b]);
        const bool il = (tp == lb - 1);
        const float gt = il ? 1.f : 1.f / (1.f + __expf(-pre));
        gatep[(size_t)b * Tsz + tp] = (tp < lb) ? gt : 0.f;
    }
}

// ---------------- host launcher ---------------------------------------------
extern "C" void kernel_launch(void* const* d_in, const int* in_sizes, int n_in,
                              void* d_out, int out_size, void* d_ws, size_t ws_size,
                              hipStream_t stream) {
    const float* x = (const float*)d_in[0];
    const float* h0 = (const float*)d_in[1];
    const int* lens = (const int*)d_in[2];
    const float* W_ih = (const float*)d_in[3];
    const float* W_hh = (const float*)d_in[4];
    const float* b_ih = (const float*)d_in[5];
    const float* b_hh = (const float*)d_in[6];
    const float* gW1 = (const float*)d_in[7];
    const float* gb1 = (const float*)d_in[8];
    const float* gW2 = (const float*)d_in[9];
    const float* gb2 = (const float*)d_in[10];
    const float* gWF = (const float*)d_in[11];
    const float* gbF = (const float*)d_in[12];
    float* outp = (float*)d_out;
    float* gatep = outp + (size_t)Bsz * Tsz * Hsz;

    hipLaunchKernelGGL(k_init, dim3(265), dim3(256), 0, stream,
                       h0, gW1, gb1, gW2, gb2, gWF, gbF);
    hipLaunchKernelGGL(k_an, dim3(256), dim3(256), 0, stream, x);
    hipLaunchKernelGGL(k_gemm, dim3(24, 128), dim3(256), 0, stream,
                       x, W_ih, b_ih);

    void* args[8] = { (void*)&h0, (void*)&lens, (void*)&W_ih, (void*)&W_hh,
                      (void*)&b_ih, (void*)&b_hh, (void*)&outp, (void*)&gatep };
    hipError_t err = hipLaunchCooperativeKernel((const void*)k_main, dim3(NWG), dim3(NTHR),
                                                args, 0, stream);
    (void)err;
}

// Round 17
// 12997.852 us; speedup vs baseline: 1.1071x; 1.1053x over previous
//
#include <hip/hip_runtime.h>
#include <cmath>

#define Bsz 64
#define Tsz 256
#define Hsz 1024
#define NWG 256
#define NTHR 512
#define GRPWG 64   // workgroups per b-group (4 groups of 64)
#define WROW 522   // padded uint stride per LDS weight row (512 used + 10 pad)

// counted vmem wait + scheduler fence (rule #18)
#define WAITVM(N) do {                                            \
    asm volatile("s_waitcnt vmcnt(" #N ")" ::: "memory");         \
    __builtin_amdgcn_sched_barrier(0);                            \
} while (0)

// ---------------- device-global scratch -------------------------------------
__device__ float g_h[2][2][Bsz * Hsz];      // [layer][parity][b*H+k]
__device__ float g_pre[2][Bsz];             // [parity][b] gate partial accum
__device__ float g_an[Tsz * Bsz];           // [t][b]: x[b,min(t+1,T-1)] . v1
__device__ float g_v1[Hsz];
__device__ float g_v2[Hsz];
__device__ float g_c;
__device__ unsigned g_bar_cnt[4 * 32];      // padded per-group barrier state
__device__ unsigned g_bar_gen[4 * 32];
__device__ float g_gi0[(size_t)Tsz * Bsz * 3 * Hsz];  // 201 MB: x@Wih0^T + bih0

// ---------------- per-access coherent ops (NO L2-invalidating fences) -------
__device__ __forceinline__ float ldc(const float* p) {
    return __hip_atomic_load((const float*)p, __ATOMIC_RELAXED,
                             __HIP_MEMORY_SCOPE_AGENT);
}
__device__ __forceinline__ void stc(float* p, float v) {
    __hip_atomic_store(p, v, __ATOMIC_RELAXED, __HIP_MEMORY_SCOPE_AGENT);
}

// coherent 16B load: ONE request; sc0 sc1 = always-fresh
__device__ __forceinline__ void ldc4_issue(const float* p, float4& v) {
    asm volatile("global_load_dwordx4 %0, %1, off sc0 sc1"
                 : "=v"(v) : "v"(p));
}

// bf16-pair (low = even k, high = odd k) -> float4 via shift/mask
__device__ __forceinline__ float4 bfx4(uint2 u) {
    float4 f;
    f.x = __uint_as_float(u.x << 16);
    f.y = __uint_as_float(u.x & 0xffff0000u);
    f.z = __uint_as_float(u.y << 16);
    f.w = __uint_as_float(u.y & 0xffff0000u);
    return f;
}

__device__ __forceinline__ unsigned rne_bf16_pair(float a, float b) {
    unsigned u0 = __float_as_uint(a);
    unsigned u1 = __float_as_uint(b);
    u0 = (u0 + 0x7fffu + ((u0 >> 16) & 1u)) >> 16;   // RNE to bf16
    u1 = (u1 + 0x7fffu + ((u1 >> 16) & 1u)) >> 16;
    return u0 | (u1 << 16);
}

// ---------------- per-b-group barrier (64 WGs) ------------------------------
__device__ __forceinline__ void groupbar(int bg, unsigned lgen) {
    __syncthreads();
    if (threadIdx.x == 0) {
        unsigned* cnt = &g_bar_cnt[bg * 32];
        unsigned* gen = &g_bar_gen[bg * 32];
        unsigned prev = __hip_atomic_fetch_add(cnt, 1u, __ATOMIC_RELAXED,
                                               __HIP_MEMORY_SCOPE_AGENT);
        if (prev == lgen * GRPWG - 1u) {
            __hip_atomic_store(gen, lgen, __ATOMIC_RELAXED,
                               __HIP_MEMORY_SCOPE_AGENT);
        } else {
            while (__hip_atomic_load(gen, __ATOMIC_RELAXED,
                                     __HIP_MEMORY_SCOPE_AGENT) < lgen)
                __builtin_amdgcn_s_sleep(1);
        }
    }
    __syncthreads();
}

// ---------------- init ------------------------------------------------------
__global__ void k_init(const float* __restrict__ h0,
                       const float* __restrict__ gW1, const float* __restrict__ gb1,
                       const float* __restrict__ gW2, const float* __restrict__ gb2,
                       const float* __restrict__ gWF, const float* __restrict__ gbF) {
    int blk = blockIdx.x, tid = threadIdx.x;
    if (blk < 256) {
        int idx = blk * 256 + tid;
        float v = h0[idx & (Hsz - 1)];
        g_h[0][0][idx] = v;
        g_h[1][0][idx] = v;
    } else if (blk == 256) {
        __shared__ float red[256];
        float s = 0.f;
        for (int j = tid; j < Hsz; j += 256) s += gWF[j] * (gb1[j] + gb2[j]);
        red[tid] = s;
        __syncthreads();
        for (int off = 128; off > 0; off >>= 1) {
            if (tid < off) red[tid] += red[tid + off];
            __syncthreads();
        }
        if (tid == 0) g_c = red[0] + gbF[0];
        if (tid < 128) ((float*)g_pre)[tid] = 0.f;
        if (tid >= 128 && tid < 256) {
            g_bar_cnt[tid - 128] = 0u;
            g_bar_gen[tid - 128] = 0u;
        }
    } else if (blk < 261) {
        int k = (blk - 257) * 256 + tid;
        float s = 0.f;
        for (int j = 0; j < Hsz; ++j) s += gWF[j] * gW1[(size_t)j * Hsz + k];
        g_v1[k] = s;
    } else {
        int k = (blk - 261) * 256 + tid;
        float s = 0.f;
        for (int j = 0; j < Hsz; ++j) s += gWF[j] * gW2[(size_t)j * Hsz + k];
        g_v2[k] = s;
    }
}

// ---------------- precompute an[t][b] = x[b, min(t+1,T-1)] . v1 -------------
__global__ void k_an(const float* __restrict__ x) {
    int blk = blockIdx.x, tid = threadIdx.x;
    int lane = tid & 63, wv = tid >> 6;
    for (int i = 0; i < 16; ++i) {
        int o = blk * 64 + wv * 16 + i;      // [0, 16384)
        int b = o >> 8, tt = o & 255;
        int ts = (tt + 1 < Tsz) ? tt + 1 : Tsz - 1;
        const float* xp = x + ((size_t)b * Tsz + ts) * Hsz;
        float s = 0.f;
        for (int k = lane; k < Hsz; k += 64) s += xp[k] * g_v1[k];
        for (int m = 32; m > 0; m >>= 1) s += __shfl_xor(s, m, 64);
        if (lane == 0) g_an[tt * 64 + b] = s;
    }
}

// ---------------- gi0 GEMM: g_gi0[t*64+b][n] = x[b,t,:].Wih0[n,:] + bih0[n] -
__global__ __launch_bounds__(256) void k_gemm(const float* __restrict__ x,
                                              const float* __restrict__ Wih,
                                              const float* __restrict__ bih) {
    __shared__ float As[16][132];
    __shared__ float Bs[16][132];
    const int tid = threadIdx.x;
    const int n0 = blockIdx.x * 128;   // 24 tiles
    const int m0 = blockIdx.y * 128;   // 128 tiles (C-row space r = t*64+b)
    const int tx = tid & 15, ty = tid >> 4;
    float acc[8][8] = {};

    for (int k0 = 0; k0 < Hsz; k0 += 16) {
#pragma unroll
        for (int i = 0; i < 2; ++i) {
            int task = tid * 2 + i;          // 0..511
            int rl = task >> 2;              // 0..127
            int kq = task & 3;
            int r = m0 + rl;
            int bb = r & 63, tt = r >> 6;
            float4 v = *(const float4*)(x + ((size_t)bb * Tsz + tt) * Hsz + k0 + kq * 4);
            As[kq * 4 + 0][rl] = v.x; As[kq * 4 + 1][rl] = v.y;
            As[kq * 4 + 2][rl] = v.z; As[kq * 4 + 3][rl] = v.w;
            float4 w = *(const float4*)(Wih + (size_t)(n0 + rl) * Hsz + k0 + kq * 4);
            Bs[kq * 4 + 0][rl] = w.x; Bs[kq * 4 + 1][rl] = w.y;
            Bs[kq * 4 + 2][rl] = w.z; Bs[kq * 4 + 3][rl] = w.w;
        }
        __syncthreads();
#pragma unroll
        for (int k = 0; k < 16; ++k) {
            float a[8], b[8];
            *(float4*)&a[0] = *(float4*)&As[k][ty * 8];
            *(float4*)&a[4] = *(float4*)&As[k][ty * 8 + 4];
            *(float4*)&b[0] = *(float4*)&Bs[k][tx * 8];
            *(float4*)&b[4] = *(float4*)&Bs[k][tx * 8 + 4];
#pragma unroll
            for (int i2 = 0; i2 < 8; ++i2)
#pragma unroll
                for (int j2 = 0; j2 < 8; ++j2) acc[i2][j2] += a[i2] * b[j2];
        }
        __syncthreads();
    }
#pragma unroll
    for (int i2 = 0; i2 < 8; ++i2) {
        int r = m0 + ty * 8 + i2;
        float* cp = g_gi0 + (size_t)r * (3 * Hsz) + n0 + tx * 8;
#pragma unroll
        for (int j2 = 0; j2 < 8; j2 += 4) {
            float4 v;
            v.x = acc[i2][j2 + 0] + bih[n0 + tx * 8 + j2 + 0];
            v.y = acc[i2][j2 + 1] + bih[n0 + tx * 8 + j2 + 1];
            v.z = acc[i2][j2 + 2] + bih[n0 + tx * 8 + j2 + 2];
            v.w = acc[i2][j2 + 3] + bih[n0 + tx * 8 + j2 + 3];
            *(float4*)(cp + j2) = v;
        }
    }
}

__device__ __forceinline__ float dot4(float4 a, float4 b) {
    return a.x * b.x + a.y * b.y + a.z * b.z + a.w * b.w;
}

// ---------------- phase A: L0 h-matmul (LDS bf16) + L1 h-matmul (L2 fp32) ---
// Both depend only on state from step t-1 (post bar2). Interleaving the LDS
// and L2 weight streams in ONE loop lets each pipe's latency hide under the
// other's compute. L1-h partial sums (axh) persist in registers across bar1.
__device__ __forceinline__ void phaseA(
    int t, int b0, int jn0,
    const float* __restrict__ st0, float* __restrict__ ho0,  // L0 state in/out
    const float* __restrict__ st1,                           // L1 state in
    const float* __restrict__ Whh1,                          // L1 recurrent W (fp32)
    const float* __restrict__ bh0,                           // b_hh layer 0
    const float* __restrict__ h0,
    const unsigned* s_wl,
    float (*s_act)[2][16][36], float (*s_red)[4][16][16],
    const float* __restrict__ s_rst,
    float (&axh)[3][2][2]) {

    const int tid = threadIdx.x;
    const int wv = tid >> 6, lane = tid & 63;
    const int bi2 = (lane & 7) * 2, ji2 = (lane >> 3) * 2;
    const int kq0 = wv * 128;

    int rb[6];
    const float* wp1[6];
#pragma unroll
    for (int g = 0; g < 3; ++g)
#pragma unroll
        for (int dj = 0; dj < 2; ++dj) {
            rb[g * 2 + dj] = (g * 16 + ji2 + dj) * WROW;
            wp1[g * 2 + dj] = Whh1 + (size_t)(g * Hsz + jn0 + ji2 + dj) * Hsz;
        }

    float acc0[3][2][2] = {};
#pragma unroll
    for (int m = 0; m < 3; ++m)
#pragma unroll
        for (int a = 0; a < 2; ++a)
#pragma unroll
            for (int d = 0; d < 2; ++d) axh[m][a][d] = 0.f;

    // stage BOTH layers' h-state for this wave's K-window (4 loads/chunk)
    auto issue_chunk = [&](int c, float4* dst) {
        const int kb = kq0 + c * 32;
#pragma unroll
        for (int i = 0; i < 4; ++i) {
            int o = (i & 1) * 64 + lane;
            int layer = i >> 1;
            int bb = (o >> 3) & 15, k4 = o & 7;
            int k = kb + k4 * 4;
            const float* p = (layer ? st1 : st0) + (size_t)(b0 + bb) * Hsz + k;
            ldc4_issue(p, dst[i]);
        }
    };
    auto patch_write = [&](int c, float4* src) {
        const int kb = kq0 + c * 32;
#pragma unroll
        for (int i = 0; i < 4; ++i) {
            int o = (i & 1) * 64 + lane;
            int layer = i >> 1;
            int bb = (o >> 3) & 15, k4 = o & 7;
            int k = kb + k4 * 4;
            float4 v = src[i];
            float4 hv = *(const float4*)(h0 + k);
            if (s_rst[bb] != 0.f) v = hv;    // reset applies to both layers
            *(float4*)&s_act[wv][layer][bb][k4 * 4] = v;
        }
    };
    auto compute_chunk = [&](int c) {
        const int kb = kq0 + c * 32;
#pragma unroll 2
        for (int kk = 0; kk < 32; kk += 4) {
            const int k = kb + kk;
            const int kw = k >> 1;
            float4 hA = *(const float4*)&s_act[wv][0][bi2][kk];
            float4 hB = *(const float4*)&s_act[wv][0][bi2 + 1][kk];
            float4 gA = *(const float4*)&s_act[wv][1][bi2][kk];
            float4 gB = *(const float4*)&s_act[wv][1][bi2 + 1][kk];
#pragma unroll
            for (int dj = 0; dj < 2; ++dj) {
                // L0: LDS bf16 weights
                float4 whr = bfx4(*(const uint2*)&s_wl[rb[0 * 2 + dj] + kw]);
                float4 whz = bfx4(*(const uint2*)&s_wl[rb[1 * 2 + dj] + kw]);
                float4 whn = bfx4(*(const uint2*)&s_wl[rb[2 * 2 + dj] + kw]);
                acc0[0][0][dj] += dot4(hA, whr);
                acc0[0][1][dj] += dot4(hB, whr);
                acc0[1][0][dj] += dot4(hA, whz);
                acc0[1][1][dj] += dot4(hB, whz);
                acc0[2][0][dj] += dot4(hA, whn);
                acc0[2][1][dj] += dot4(hB, whn);
                // L1-h: fp32 weights streamed from L2 (overlaps LDS stream)
                float4 w1r = *(const float4*)(wp1[0 * 2 + dj] + k);
                float4 w1z = *(const float4*)(wp1[1 * 2 + dj] + k);
                float4 w1n = *(const float4*)(wp1[2 * 2 + dj] + k);
                axh[0][0][dj] += dot4(gA, w1r);
                axh[0][1][dj] += dot4(gB, w1r);
                axh[1][0][dj] += dot4(gA, w1z);
                axh[1][1][dj] += dot4(gB, w1z);
                axh[2][0][dj] += dot4(gA, w1n);
                axh[2][1][dj] += dot4(gB, w1n);
            }
        }
    };

    float4 C0[4], C1[4], C2[4], C3[4];
    issue_chunk(0, C0); issue_chunk(1, C1);
    issue_chunk(2, C2); issue_chunk(3, C3);
    WAITVM(12);
    patch_write(0, C0); compute_chunk(0);
    WAITVM(8);
    patch_write(1, C1); compute_chunk(1);
    WAITVM(4);
    patch_write(2, C2); compute_chunk(2);
    WAITVM(0);
    patch_write(3, C3); compute_chunk(3);

    // ---- two-stage cross-wave reduce (L0 only; NM=3) ------------------------
    __syncthreads();
    if (wv >= 4) {
#pragma unroll
        for (int m = 0; m < 3; ++m)
#pragma unroll
            for (int db = 0; db < 2; ++db)
#pragma unroll
                for (int dj = 0; dj < 2; ++dj)
                    s_red[wv - 4][m][bi2 + db][ji2 + dj] = acc0[m][db][dj];
    }
    __syncthreads();
    if (wv < 4) {
#pragma unroll
        for (int m = 0; m < 3; ++m)
#pragma unroll
            for (int db = 0; db < 2; ++db)
#pragma unroll
                for (int dj = 0; dj < 2; ++dj)
                    s_red[wv][m][bi2 + db][ji2 + dj] += acc0[m][db][dj];
    }
    __syncthreads();

    // ---- L0 epilogue --------------------------------------------------------
    if (tid < 256) {
        const int ji = tid & 15, bI = tid >> 4;
        const int b = b0 + bI, jn = jn0 + ji;
        float hprev = ldc(st0 + (size_t)b * Hsz + jn);
        const float* gp = g_gi0 + (size_t)(t * 64 + b) * (3 * Hsz) + jn;
        float g0r = gp[0];
        float g0z = gp[Hsz];
        float g0n = gp[2 * Hsz];
        float s[3];
#pragma unroll
        for (int m = 0; m < 3; ++m)
            s[m] = s_red[0][m][bI][ji] + s_red[1][m][bI][ji] +
                   s_red[2][m][bI][ji] + s_red[3][m][bI][ji];
        if (s_rst[bI] != 0.f) hprev = h0[jn];

        const float pr  = g0r + s[0] + bh0[jn];
        const float pz  = g0z + s[1] + bh0[Hsz + jn];
        const float pin = g0n;
        const float phn = s[2] + bh0[2 * Hsz + jn];
        const float r_ = 1.f / (1.f + __expf(-pr));
        const float z_ = 1.f / (1.f + __expf(-pz));
        const float n_ = tanhf(pin + r_ * phn);
        const float hnew = (1.f - z_) * n_ + z_ * hprev;
        stc(ho0 + (size_t)b * Hsz + jn, hnew);               // coherent state write
    }
}

// ---------------- phase B: L1 x-matmul + epilogue (merges axh) --------------
__device__ __forceinline__ void phaseB(
    int t, int b0, int jn0,
    const float* __restrict__ a0,                            // h_L0(t) (no patch)
    const float* __restrict__ st, float* __restrict__ ho,    // L1 state in/out
    const float* __restrict__ Wih1,
    const float* __restrict__ bi, const float* __restrict__ bh,
    const float* __restrict__ h0, const int* __restrict__ lens,
    float* __restrict__ outp,
    float (*s_act)[2][16][36], float (*s_red)[4][16][16],
    const float* __restrict__ s_rst, float (*s_gs)[16],
    const float (&axh)[3][2][2]) {

    const int tid = threadIdx.x;
    const int wv = tid >> 6, lane = tid & 63;
    const int bi2 = (lane & 7) * 2, ji2 = (lane >> 3) * 2;
    const int kq0 = wv * 128;

    const float* wpi[6];
#pragma unroll
    for (int g = 0; g < 3; ++g)
#pragma unroll
        for (int dj = 0; dj < 2; ++dj)
            wpi[g * 2 + dj] = Wih1 + (size_t)(g * Hsz + jn0 + ji2 + dj) * Hsz;

    float acc[3][2][2] = {};   // x-parts: 0=i_r, 1=i_z, 2=i_n

    auto issue_chunk = [&](int c, float4* dst) {
        const int kb = kq0 + c * 32;
#pragma unroll
        for (int i = 0; i < 2; ++i) {
            int o = i * 64 + lane;
            int bb = (o >> 3) & 15, k4 = o & 7;
            int k = kb + k4 * 4;
            ldc4_issue(a0 + (size_t)(b0 + bb) * Hsz + k, dst[i]);
        }
    };
    auto write_chunk = [&](int c, float4* src) {
#pragma unroll
        for (int i = 0; i < 2; ++i) {
            int o = i * 64 + lane;
            int bb = (o >> 3) & 15, k4 = o & 7;
            *(float4*)&s_act[wv][0][bb][k4 * 4] = src[i];   // no reset patch (pre-reset h_L0)
        }
    };
    auto compute_chunk = [&](int c) {
        const int kb = kq0 + c * 32;
#pragma unroll 2
        for (int kk = 0; kk < 32; kk += 4) {
            const int k = kb + kk;
            float4 xA = *(const float4*)&s_act[wv][0][bi2][kk];
            float4 xB = *(const float4*)&s_act[wv][0][bi2 + 1][kk];
#pragma unroll
            for (int dj = 0; dj < 2; ++dj) {
                float4 wir = *(const float4*)(wpi[0 * 2 + dj] + k);
                float4 wiz = *(const float4*)(wpi[1 * 2 + dj] + k);
                float4 win = *(const float4*)(wpi[2 * 2 + dj] + k);
                acc[0][0][dj] += dot4(xA, wir);
                acc[0][1][dj] += dot4(xB, wir);
                acc[1][0][dj] += dot4(xA, wiz);
                acc[1][1][dj] += dot4(xB, wiz);
                acc[2][0][dj] += dot4(xA, win);
                acc[2][1][dj] += dot4(xB, win);
            }
        }
    };

    float4 C0[2], C1[2], C2[2], C3[2];
    issue_chunk(0, C0); issue_chunk(1, C1);
    issue_chunk(2, C2); issue_chunk(3, C3);
    WAITVM(6);
    write_chunk(0, C0); compute_chunk(0);
    WAITVM(4);
    write_chunk(1, C1); compute_chunk(1);
    WAITVM(2);
    write_chunk(2, C2); compute_chunk(2);
    WAITVM(0);
    write_chunk(3, C3); compute_chunk(3);

    // merge register-carried h-parts from phase A, then reduce (NM=4)
    float m4[4][2][2];
#pragma unroll
    for (int db = 0; db < 2; ++db)
#pragma unroll
        for (int dj = 0; dj < 2; ++dj) {
            m4[0][db][dj] = acc[0][db][dj] + axh[0][db][dj];
            m4[1][db][dj] = acc[1][db][dj] + axh[1][db][dj];
            m4[2][db][dj] = acc[2][db][dj];
            m4[3][db][dj] = axh[2][db][dj];
        }

    __syncthreads();
    if (wv >= 4) {
#pragma unroll
        for (int m = 0; m < 4; ++m)
#pragma unroll
            for (int db = 0; db < 2; ++db)
#pragma unroll
                for (int dj = 0; dj < 2; ++dj)
                    s_red[wv - 4][m][bi2 + db][ji2 + dj] = m4[m][db][dj];
    }
    __syncthreads();
    if (wv < 4) {
#pragma unroll
        for (int m = 0; m < 4; ++m)
#pragma unroll
            for (int db = 0; db < 2; ++db)
#pragma unroll
                for (int dj = 0; dj < 2; ++dj)
                    s_red[wv][m][bi2 + db][ji2 + dj] += m4[m][db][dj];
    }
    __syncthreads();

    // ---- L1 epilogue --------------------------------------------------------
    if (tid < 256) {
        const int ji = tid & 15, bI = tid >> 4;
        const int b = b0 + bI, jn = jn0 + ji;
        float hprev = ldc(st + (size_t)b * Hsz + jn);
        const int lb = lens[b];
        float s[4];
#pragma unroll
        for (int m = 0; m < 4; ++m)
            s[m] = s_red[0][m][bI][ji] + s_red[1][m][bI][ji] +
                   s_red[2][m][bI][ji] + s_red[3][m][bI][ji];
        if (s_rst[bI] != 0.f) hprev = h0[jn];

        const float pr  = s[0] + bi[jn] + bh[jn];
        const float pz  = s[1] + bi[Hsz + jn] + bh[Hsz + jn];
        const float pin = s[2] + bi[2 * Hsz + jn];
        const float phn = s[3] + bh[2 * Hsz + jn];
        const float r_ = 1.f / (1.f + __expf(-pr));
        const float z_ = 1.f / (1.f + __expf(-pz));
        const float n_ = tanhf(pin + r_ * phn);
        const float hnew = (1.f - z_) * n_ + z_ * hprev;
        stc(ho + (size_t)b * Hsz + jn, hnew);                // coherent state write
        outp[((size_t)b * Tsz + t) * Hsz + jn] = (t < lb) ? hnew : 0.f;
        s_gs[bI][ji] = hnew * g_v2[jn];
    }
    __syncthreads();
    if (tid < 16) {
        float sm = 0.f;
#pragma unroll
        for (int j = 0; j < 16; ++j) sm += s_gs[tid][j];
        atomicAdd(&g_pre[t & 1][b0 + tid], sm);
    }
}

// ---------------- main persistent cooperative kernel ------------------------
// R13 config + phase rebalance: phase A = L0-h (LDS) + L1-h (L2) interleaved,
// phase B = L1-x only. axh carries L1-h partials across bar1 in registers.
__global__ void __launch_bounds__(NTHR, 1)
k_main(const float* __restrict__ h0, const int* __restrict__ lens,
       const float* __restrict__ W_ih, const float* __restrict__ W_hh,
       const float* __restrict__ b_ih, const float* __restrict__ b_hh,
       float* __restrict__ outp, float* __restrict__ gatep) {
    __shared__ __align__(16) unsigned s_w[48 * WROW];    // 100.2 KB bf16 L0-Whh
    __shared__ __align__(16) float s_act[8][2][16][36];  // 36.9 KB
    __shared__ float s_red[4][4][16][16];                // 16.4 KB
    __shared__ float s_rst[16];
    __shared__ float s_gs[16][16];

    const int tid = threadIdx.x;
    const int wg = blockIdx.x, bg = wg >> 6, jg = wg & 63;
    const int b0 = bg * 16, jn0 = jg * 16;
    unsigned lgen = 0;

    const float* Wih1 = W_ih + (size_t)3 * Hsz * Hsz;
    const float* Whh1 = W_hh + (size_t)3 * Hsz * Hsz;
    const float* bi1 = b_ih + 3 * Hsz;
    const float* bh1 = b_hh + 3 * Hsz;

    // one-time: pack this WG's 48 L0-Whh rows into LDS as bf16 (RNE) pairs
    for (int idx = tid; idx < 48 * 512; idx += NTHR) {
        int r = idx >> 9, kw = idx & 511;
        int g = r >> 4, j = r & 15;
        const float* wrow = W_hh + ((size_t)(g * Hsz + jn0 + j)) * Hsz + kw * 2;
        s_w[r * WROW + kw] = rne_bf16_pair(wrow[0], wrow[1]);
    }
    __syncthreads();

    float axh[3][2][2];

    for (int t = 0; t < Tsz; ++t) {
        const int p0 = t & 1, p1 = p0 ^ 1;

        // prologue: reset flags from previous step's gate; emit gate_z
        if (tid < 16) {
            float rstf = 0.f;
            const int b = b0 + tid;
            const int lb = lens[b];
            if (t > 0) {
                const int tp = t - 1;
                const float pre = g_c + g_an[tp * 64 + b] + ldc(&g_pre[p1][b]);
                const bool il = (tp == lb - 1);
                rstf = (il || pre > 0.f) ? 1.f : 0.f;
                if (jg == 0) {
                    const float gt = il ? 1.f : 1.f / (1.f + __expf(-pre));
                    gatep[(size_t)b * Tsz + tp] = (tp < lb) ? gt : 0.f;
                }
            }
            s_rst[tid] = rstf;
        }
        __syncthreads();

        // phase A: L0 (gi from g_gi0, h from LDS bf16) + L1-h (fp32 L2)
        phaseA(t, b0, jn0,
               g_h[0][p0], g_h[0][p1], g_h[1][p0],
               Whh1, b_hh, h0, s_w, s_act, s_red, s_rst, axh);
        groupbar(bg, ++lgen);

        // zero next step's gate accumulator (parity p1, already consumed)
        if (jg == 0 && tid < 16) stc(&g_pre[p1][b0 + tid], 0.f);

        // phase B: L1-x from fresh h_L0(t) + merged epilogue
        phaseB(t, b0, jn0,
               g_h[0][p1], g_h[1][p0], g_h[1][p1],
               Wih1, bi1, bh1, h0, lens,
               outp, s_act, s_red, s_rst, s_gs, axh);
        groupbar(bg, ++lgen);
    }

    // tail: gate_z for tp = T-1
    if (jg == 0 && tid < 16) {
        const int b = b0 + tid;
        const int lb = lens[b];
        const int tp = Tsz - 1;
        const float pre = g_c + g_an[tp * 64 + b] + ldc(&g_pre[tp & 1][b]);
        const bool il = (tp == lb - 1);
        const float gt = il ? 1.f : 1.f / (1.f + __expf(-pre));
        gatep[(size_t)b * Tsz + tp] = (tp < lb) ? gt : 0.f;
    }
}

// ---------------- host launcher ---------------------------------------------
extern "C" void kernel_launch(void* const* d_in, const int* in_sizes, int n_in,
                              void* d_out, int out_size, void* d_ws, size_t ws_size,
                              hipStream_t stream) {
    const float* x = (const float*)d_in[0];
    const float* h0 = (const float*)d_in[1];
    const int* lens = (const int*)d_in[2];
    const float* W_ih = (const float*)d_in[3];
    const float* W_hh = (const float*)d_in[4];
    const float* b_ih = (const float*)d_in[5];
    const float* b_hh = (const float*)d_in[6];
    const float* gW1 = (const float*)d_in[7];
    const float* gb1 = (const float*)d_in[8];
    const float* gW2 = (const float*)d_in[9];
    const float* gb2 = (const float*)d_in[10];
    const float* gWF = (const float*)d_in[11];
    const float* gbF = (const float*)d_in[12];
    float* outp = (float*)d_out;
    float* gatep = outp + (size_t)Bsz * Tsz * Hsz;

    hipLaunchKernelGGL(k_init, dim3(265), dim3(256), 0, stream,
                       h0, gW1, gb1, gW2, gb2, gWF, gbF);
    hipLaunchKernelGGL(k_an, dim3(256), dim3(256), 0, stream, x);
    hipLaunchKernelGGL(k_gemm, dim3(24, 128), dim3(256), 0, stream,
                       x, W_ih, b_ih);

    void* args[8] = { (void*)&h0, (void*)&lens, (void*)&W_ih, (void*)&W_hh,
                      (void*)&b_ih, (void*)&b_hh, (void*)&outp, (void*)&gatep };
    hipError_t err = hipLaunchCooperativeKernel((const void*)k_main, dim3(NWG), dim3(NTHR),
                                                args, 0, stream);
    (void)err;
}